// Round 2
// baseline (535.659 us; speedup 1.0000x reference)
//
#include <hip/hip_runtime.h>
#include <hip/hip_bf16.h>
#include <hip/hip_fp16.h>

#define B_   16
#define S_   4096
#define D_   512
#define DH_  256
#define M_   (B_ * S_)      // 65536 rows
#define LC   64             // GARCH chunk length
#define NCH  (S_ / LC)      // 64 chunks

typedef _Float16 f16x8 __attribute__((ext_vector_type(8)));
typedef float    f32x4 __attribute__((ext_vector_type(4)));

// -------- async global->LDS, 16B per lane (linear LDS dest, per-lane global src) -----
__device__ __forceinline__ void async_copy16(void* lds, const void* g) {
  __builtin_amdgcn_global_load_lds(
      (const __attribute__((address_space(1))) void*)g,
      (__attribute__((address_space(3))) void*)lds, 16, 0, 0);
}

// ---------------- weight transpose + f16 convert: dst[c][r] = src[r][c] -------------
__global__ void transpose_to_f16(const float* __restrict__ src, _Float16* __restrict__ dst,
                                 int Rr, int Cc) {
  const int idx = blockIdx.x * 256 + threadIdx.x;   // over Rr*Cc
  const int c = idx / Rr;
  const int r = idx - c * Rr;
  dst[idx] = (_Float16)src[(size_t)r * Cc + c];     // coalesced writes
}

// ---------------- GARCH phase 1: per-chunk affine coefficient C ---------------------
// Over chunk c: V_{c+1} = beta^LC * V_c + C_c,  C_c = recurrence started from 0.
__global__ void garch_chunk(const float* __restrict__ ret,
                            const float* __restrict__ pal, const float* __restrict__ pbe,
                            const float* __restrict__ pom, float* __restrict__ Cws) {
  const int d  = threadIdx.x;          // 0..511
  const int bc = blockIdx.x;           // b*NCH + c
  const int b  = bc >> 6;
  const int c  = bc & (NCH - 1);
  const float al = pal[0], be = pbe[0], om = pom[0];
  const float* rp = ret + ((size_t)(b * S_ + c * LC)) * D_ + d;
  float Ca = 0.f;
#pragma unroll 8
  for (int j = 0; j < LC; j++) {
    const float r = rp[(size_t)j * D_];            // coalesced across d
    Ca = fmaf(be, Ca, fmaf(al, r * r, om));
  }
  Cws[(size_t)bc * D_ + d] = Ca;
}

// ---------------- GARCH phase 2: scan over chunks (A = beta^64 uniform) -------------
__global__ void garch_scan(const float* __restrict__ pbe, const float* __restrict__ Cws,
                           float* __restrict__ Vws) {
  const int d = threadIdx.x;
  const int b = blockIdx.x;
  float A = pbe[0];
  A = A * A; A = A * A; A = A * A; A = A * A; A = A * A; A = A * A;   // beta^64
  float V = 0.01f;                                                     // INIT_VAR
  for (int c = 0; c < NCH; c++) {
    const size_t idx = ((size_t)(b * NCH + c)) * D_ + d;
    Vws[idx] = V;
    V = fmaf(A, V, Cws[idx]);
  }
}

// ---------------- GARCH phase 3: replay chunk, write cond_var into d_out ------------
__global__ void garch_replay(const float* __restrict__ ret,
                             const float* __restrict__ pal, const float* __restrict__ pbe,
                             const float* __restrict__ pom, const float* __restrict__ Vws,
                             float* __restrict__ out) {
  const int d  = threadIdx.x;
  const int bc = blockIdx.x;
  const int b  = bc >> 6;
  const int c  = bc & (NCH - 1);
  const float al = pal[0], be = pbe[0], om = pom[0];
  const size_t base = ((size_t)(b * S_ + c * LC)) * D_ + d;
  float v = Vws[(size_t)bc * D_ + d];
  out[base] = v;
  const float* rp = ret + base;
#pragma unroll 8
  for (int j = 1; j < LC; j++) {
    const float r = rp[(size_t)(j - 1) * D_];
    v = fmaf(be, v, fmaf(al, r * r, om));
    out[base + (size_t)j * D_] = v;
  }
}

// ---------------- f16 MFMA GEMM: 128x128 tile, BK=64, XOR-swizzled LDS --------------
// MODE 0: A = fp32 (convert in staging), out = relu(acc+bias) as f16   (h = x@W1+b1)
// MODE 1: A = f16 (global_load_lds),     out = softplus(acc+bias)*cv   (final output)
template<int KDIM, int NOUT, int MODE>
__launch_bounds__(256, 2)
__global__ void gemm_f16(const void* __restrict__ Ap, const _Float16* __restrict__ Bt,
                         const float* __restrict__ bias, const float* cvin,
                         void* outp) {
  __shared__ _Float16 As[128 * 64];   // [row][k], 128B rows, chunk ^= (row&7) swizzle
  __shared__ _Float16 Bs[128 * 64];   // B^T tile: [n][k]
  const int tid  = threadIdx.x;
  const int lane = tid & 63;
  const int w    = tid >> 6;
  const int wm   = w >> 1, wn = w & 1;          // 2x2 wave grid, 64x64 per wave
  const size_t m0 = (size_t)blockIdx.x * 128;
  const int    n0 = blockIdx.y * 128;

  f32x4 acc[4][4];
#pragma unroll
  for (int i = 0; i < 4; i++)
#pragma unroll
    for (int j = 0; j < 4; j++)
      acc[i][j] = (f32x4){0.f, 0.f, 0.f, 0.f};

  const _Float16* hA = (const _Float16*)Ap;
  const float*    fA = (const float*)Ap;

  for (int kt = 0; kt < KDIM; kt += 64) {
    // ---- stage B (f16, pre-transposed): linear LDS dest + inverse-swizzled source ----
#pragma unroll
    for (int rr = 0; rr < 4; rr++) {
      const int task = rr * 256 + tid;
      const int row = task >> 3, pos = task & 7;
      const int dc = pos ^ (row & 7);
      async_copy16(&Bs[task * 8], &Bt[(size_t)(n0 + row) * KDIM + kt + dc * 8]);
    }
    if (MODE == 1) {
#pragma unroll
      for (int rr = 0; rr < 4; rr++) {
        const int task = rr * 256 + tid;
        const int row = task >> 3, pos = task & 7;
        const int dc = pos ^ (row & 7);
        async_copy16(&As[task * 8], &hA[(m0 + row) * (size_t)KDIM + kt + dc * 8]);
      }
    } else {
      // fp32 -> f16 reg-staged convert, swizzled ds_write_b128
#pragma unroll
      for (int rr = 0; rr < 4; rr++) {
        const int task = rr * 256 + tid;
        const int row = task >> 3, dc = task & 7;
        const float* sp = &fA[(m0 + row) * (size_t)KDIM + kt + dc * 8];
        const float4 v0 = *(const float4*)(sp);
        const float4 v1 = *(const float4*)(sp + 4);
        f16x8 hv;
        hv[0] = (_Float16)v0.x; hv[1] = (_Float16)v0.y;
        hv[2] = (_Float16)v0.z; hv[3] = (_Float16)v0.w;
        hv[4] = (_Float16)v1.x; hv[5] = (_Float16)v1.y;
        hv[6] = (_Float16)v1.z; hv[7] = (_Float16)v1.w;
        const int pos = dc ^ (row & 7);
        *(f16x8*)&As[row * 64 + pos * 8] = hv;
      }
    }
    __syncthreads();   // compiler drains vmcnt+lgkmcnt before s_barrier

    // ---- fragments (swizzled ds_read_b128, conflict-free) + MFMA ----
    f16x8 af[4][2], bf[4][2];
#pragma unroll
    for (int f = 0; f < 4; f++) {
#pragma unroll
      for (int kk = 0; kk < 2; kk++) {
        const int k8 = kk * 4 + (lane >> 4);
        const int ar = wm * 64 + f * 16 + (lane & 15);
        af[f][kk] = *(const f16x8*)&As[ar * 64 + ((k8 ^ (ar & 7)) * 8)];
        const int br = wn * 64 + f * 16 + (lane & 15);
        bf[f][kk] = *(const f16x8*)&Bs[br * 64 + ((k8 ^ (br & 7)) * 8)];
      }
    }
#pragma unroll
    for (int kk = 0; kk < 2; kk++)
#pragma unroll
      for (int fm = 0; fm < 4; fm++)
#pragma unroll
        for (int fn = 0; fn < 4; fn++)
          acc[fm][fn] = __builtin_amdgcn_mfma_f32_16x16x32_f16(af[fm][kk], bf[fn][kk],
                                                               acc[fm][fn], 0, 0, 0);
    __syncthreads();
  }

  // ---- epilogue: C layout col=lane&15, row=(lane>>4)*4+j (m89-verified) ----
  if (MODE == 0) {
    _Float16* ho = (_Float16*)outp;
#pragma unroll
    for (int fm = 0; fm < 4; fm++) {
      const int row = wm * 64 + fm * 16 + (lane >> 4) * 4;
#pragma unroll
      for (int fn = 0; fn < 4; fn++) {
        const int col = n0 + wn * 64 + fn * 16 + (lane & 15);
        const float bv = bias[col];
#pragma unroll
        for (int j = 0; j < 4; j++) {
          float v = acc[fm][fn][j] + bv;
          v = fmaxf(v, 0.f);
          ho[(m0 + row + j) * (size_t)NOUT + col] = (_Float16)v;
        }
      }
    }
  } else {
    float* oo = (float*)outp;
#pragma unroll
    for (int fm = 0; fm < 4; fm++) {
      const int row = wm * 64 + fm * 16 + (lane >> 4) * 4;
#pragma unroll
      for (int fn = 0; fn < 4; fn++) {
        const int col = n0 + wn * 64 + fn * 16 + (lane & 15);
        const float bv = bias[col];
#pragma unroll
        for (int j = 0; j < 4; j++) {
          const float v = acc[fm][fn][j] + bv;
          // jax.nn.softplus = max(x,0) + log1p(exp(-|x|))
          const float sp = fmaxf(v, 0.f) + log1pf(expf(-fabsf(v)));
          const size_t oi = (m0 + row + j) * (size_t)NOUT + col;
          oo[oi] = sp * cvin[oi];   // cvin==outp: same lane reads then writes same elem
        }
      }
    }
  }
}

extern "C" void kernel_launch(void* const* d_in, const int* in_sizes, int n_in,
                              void* d_out, int out_size, void* d_ws, size_t ws_size,
                              hipStream_t stream) {
  const float* x     = (const float*)d_in[0];
  const float* rets  = (const float*)d_in[1];
  const float* alpha = (const float*)d_in[2];
  const float* beta  = (const float*)d_in[3];
  const float* omega = (const float*)d_in[4];
  const float* W1    = (const float*)d_in[5];
  const float* b1    = (const float*)d_in[6];
  const float* W2    = (const float*)d_in[7];
  const float* b2    = (const float*)d_in[8];
  float* out = (float*)d_out;

  // workspace layout (~36.5 MB total)
  char* ws = (char*)d_ws;
  _Float16* W1T = (_Float16*)ws;                               // [256][512] f16, 256 KB
  _Float16* W2T = (_Float16*)(ws + (256 << 10));               // [512][256] f16, 256 KB
  float*    Cws = (float*)(ws + (512 << 10));                  // [B][NCH][D] f32, 2 MB
  float*    Vws = (float*)(ws + (512 << 10) + (2 << 20));      // [B][NCH][D] f32, 2 MB
  _Float16* h   = (_Float16*)(ws + (512 << 10) + (4 << 20));   // [M][DH] f16, 32 MB

  // weight prep (tiny)
  transpose_to_f16<<<512, 256, 0, stream>>>(W1, W1T, 512, 256);  // W1T[f][d]=W1[d][f]
  transpose_to_f16<<<512, 256, 0, stream>>>(W2, W2T, 256, 512);  // W2T[d][f]=W2[f][d]

  // GARCH blocked affine scan; cond_var lands in d_out
  garch_chunk <<<B_ * NCH, 512, 0, stream>>>(rets, alpha, beta, omega, Cws);
  garch_scan  <<<B_,       512, 0, stream>>>(beta, Cws, Vws);
  garch_replay<<<B_ * NCH, 512, 0, stream>>>(rets, alpha, beta, omega, Vws, out);

  // h = relu(x @ W1 + b1)  [f16 out]
  gemm_f16<512, 256, 0><<<dim3(M_ / 128, 2), 256, 0, stream>>>(x, W1T, b1, nullptr, h);
  // out = softplus(h @ W2 + b2) * cond_var   (reads cv from d_out, writes d_out)
  gemm_f16<256, 512, 1><<<dim3(M_ / 128, 4), 256, 0, stream>>>(h, W2T, b2, out, out);
}

// Round 9
// 466.762 us; speedup vs baseline: 1.1476x; 1.1476x over previous
//
#include <hip/hip_runtime.h>
#include <hip/hip_bf16.h>
#include <hip/hip_fp16.h>

#define B_   16
#define S_   4096
#define D_   512
#define DH_  256
#define M_   (B_ * S_)      // 65536 rows
#define LC   64             // GARCH chunk length
#define NCH  (S_ / LC)      // 64 chunks

typedef _Float16 f16x8 __attribute__((ext_vector_type(8)));
typedef _Float16 f16x4 __attribute__((ext_vector_type(4)));
typedef float    f32x4 __attribute__((ext_vector_type(4)));

// -------- async global->LDS, 16B per lane (linear LDS dest, per-lane global src) -----
__device__ __forceinline__ void async_copy16(void* lds, const void* g) {
  __builtin_amdgcn_global_load_lds(
      (const __attribute__((address_space(1))) void*)g,
      (__attribute__((address_space(3))) void*)lds, 16, 0, 0);
}

// cheap softplus: max(x,0) + ln2*log2(1+2^(-|x|*log2e));
// exp2f/log2f lower to near-bare v_exp_f32/v_log_f32 (no libm range reduction)
__device__ __forceinline__ float softplus_f(float x) {
  const float t = exp2f(-fabsf(x) * 1.44269504f);
  return fmaxf(x, 0.f) + 0.69314718f * __log2f(1.f + t);
}

// ---------------- weight transpose + f16 convert: dst[c][r] = src[r][c] -------------
__global__ void transpose_to_f16(const float* __restrict__ src, _Float16* __restrict__ dst,
                                 int Rr, int Cc) {
  const int idx = blockIdx.x * 256 + threadIdx.x;   // over Rr*Cc
  const int c = idx / Rr;
  const int r = idx - c * Rr;
  dst[idx] = (_Float16)src[(size_t)r * Cc + c];     // coalesced writes
}

// ---------------- GARCH phase 1: per-chunk affine coefficient C ---------------------
__global__ void garch_chunk(const float* __restrict__ ret,
                            const float* __restrict__ pal, const float* __restrict__ pbe,
                            const float* __restrict__ pom, float* __restrict__ Cws) {
  const int d  = threadIdx.x;          // 0..511
  const int bc = blockIdx.x;           // b*NCH + c
  const int b  = bc >> 6;
  const int c  = bc & (NCH - 1);
  const float al = pal[0], be = pbe[0], om = pom[0];
  const float* rp = ret + ((size_t)(b * S_ + c * LC)) * D_ + d;
  float Ca = 0.f;
#pragma unroll 8
  for (int j = 0; j < LC; j++) {
    const float r = rp[(size_t)j * D_];            // coalesced across d
    Ca = fmaf(be, Ca, fmaf(al, r * r, om));
  }
  Cws[(size_t)bc * D_ + d] = Ca;
}

// ---------------- GARCH phase 2: scan over chunks (A = beta^64 uniform) -------------
__global__ void garch_scan(const float* __restrict__ pbe, const float* __restrict__ Cws,
                           float* __restrict__ Vws) {
  const int d = threadIdx.x;
  const int b = blockIdx.x;
  float A = pbe[0];
  A = A * A; A = A * A; A = A * A; A = A * A; A = A * A; A = A * A;   // beta^64
  float V = 0.01f;                                                     // INIT_VAR
  for (int c = 0; c < NCH; c++) {
    const size_t idx = ((size_t)(b * NCH + c)) * D_ + d;
    Vws[idx] = V;
    V = fmaf(A, V, Cws[idx]);
  }
}

// ---------------- GARCH phase 3: replay chunk, write cond_var into d_out ------------
__global__ void garch_replay(const float* __restrict__ ret,
                             const float* __restrict__ pal, const float* __restrict__ pbe,
                             const float* __restrict__ pom, const float* __restrict__ Vws,
                             float* __restrict__ out) {
  const int d  = threadIdx.x;
  const int bc = blockIdx.x;
  const int b  = bc >> 6;
  const int c  = bc & (NCH - 1);
  const float al = pal[0], be = pbe[0], om = pom[0];
  const size_t base = ((size_t)(b * S_ + c * LC)) * D_ + d;
  float v = Vws[(size_t)bc * D_ + d];
  out[base] = v;
  const float* rp = ret + base;
#pragma unroll 8
  for (int j = 1; j < LC; j++) {
    const float r = rp[(size_t)(j - 1) * D_];
    v = fmaf(be, v, fmaf(al, r * r, om));
    out[base + (size_t)j * D_] = v;
  }
}

// ---------------- f16 MFMA GEMM: 128x128 tile, BK=64, XOR-swizzled LDS --------------
// MODE 0: A = fp32 (convert in staging), out = relu(acc+bias) as f16   (h = x@W1+b1)
// MODE 1: A = f16 (global_load_lds),     out = softplus(acc+bias)*cv   (final output)
// Epilogue: stage acc+bias in LDS (f32, XOR bank-swizzle), write out coalesced.
template<int KDIM, int NOUT, int MODE>
__launch_bounds__(256, 3)   // 3 blocks/CU: 96KB LDS, ~140 regs/thread fits 512/3=170
__global__ void gemm_f16(const void* __restrict__ Ap, const _Float16* __restrict__ Bt,
                         const float* __restrict__ bias, const float* cvin,
                         void* outp) {
  __shared__ __align__(16) char smem[32768];
  _Float16* As = (_Float16*)smem;            // [128][64] f16, chunk ^= (row&7) swizzle
  _Float16* Bs = (_Float16*)(smem + 16384);  // B^T tile [n][k]
  float*    Cs = (float*)smem;               // epilogue: [128][64] f32 (reuses As+Bs)

  const int tid  = threadIdx.x;
  const int lane = tid & 63;
  const int w    = tid >> 6;
  const int wm   = w >> 1, wn = w & 1;          // 2x2 wave grid, 64x64 per wave
  const size_t m0 = (size_t)blockIdx.x * 128;
  const int    n0 = blockIdx.y * 128;

  f32x4 acc[4][4];
#pragma unroll
  for (int i = 0; i < 4; i++)
#pragma unroll
    for (int j = 0; j < 4; j++)
      acc[i][j] = (f32x4){0.f, 0.f, 0.f, 0.f};

  const _Float16* hA = (const _Float16*)Ap;
  const float*    fA = (const float*)Ap;

  for (int kt = 0; kt < KDIM; kt += 64) {
    // ---- stage B (f16, pre-transposed): linear LDS dest + inverse-swizzled source ----
#pragma unroll
    for (int rr = 0; rr < 4; rr++) {
      const int task = rr * 256 + tid;
      const int row = task >> 3, pos = task & 7;
      const int dc = pos ^ (row & 7);
      async_copy16(&Bs[task * 8], &Bt[(size_t)(n0 + row) * KDIM + kt + dc * 8]);
    }
    if (MODE == 1) {
#pragma unroll
      for (int rr = 0; rr < 4; rr++) {
        const int task = rr * 256 + tid;
        const int row = task >> 3, pos = task & 7;
        const int dc = pos ^ (row & 7);
        async_copy16(&As[task * 8], &hA[(m0 + row) * (size_t)KDIM + kt + dc * 8]);
      }
    } else {
      // fp32 -> f16 reg-staged convert, swizzled ds_write_b128
#pragma unroll
      for (int rr = 0; rr < 4; rr++) {
        const int task = rr * 256 + tid;
        const int row = task >> 3, dc = task & 7;
        const float* sp = &fA[(m0 + row) * (size_t)KDIM + kt + dc * 8];
        const float4 v0 = *(const float4*)(sp);
        const float4 v1 = *(const float4*)(sp + 4);
        f16x8 hv;
        hv[0] = (_Float16)v0.x; hv[1] = (_Float16)v0.y;
        hv[2] = (_Float16)v0.z; hv[3] = (_Float16)v0.w;
        hv[4] = (_Float16)v1.x; hv[5] = (_Float16)v1.y;
        hv[6] = (_Float16)v1.z; hv[7] = (_Float16)v1.w;
        const int pos = dc ^ (row & 7);
        *(f16x8*)&As[row * 64 + pos * 8] = hv;
      }
    }
    __syncthreads();   // compiler drains vmcnt+lgkmcnt before s_barrier

    // ---- fragments (swizzled ds_read_b128, conflict-free) + MFMA ----
    f16x8 af[4][2], bf[4][2];
#pragma unroll
    for (int f = 0; f < 4; f++) {
#pragma unroll
      for (int kk = 0; kk < 2; kk++) {
        const int k8 = kk * 4 + (lane >> 4);
        const int ar = wm * 64 + f * 16 + (lane & 15);
        af[f][kk] = *(const f16x8*)&As[ar * 64 + ((k8 ^ (ar & 7)) * 8)];
        const int br = wn * 64 + f * 16 + (lane & 15);
        bf[f][kk] = *(const f16x8*)&Bs[br * 64 + ((k8 ^ (br & 7)) * 8)];
      }
    }
#pragma unroll
    for (int kk = 0; kk < 2; kk++)
#pragma unroll
      for (int fm = 0; fm < 4; fm++)
#pragma unroll
        for (int fn = 0; fn < 4; fn++)
          acc[fm][fn] = __builtin_amdgcn_mfma_f32_16x16x32_f16(af[fm][kk], bf[fn][kk],
                                                               acc[fm][fn], 0, 0, 0);
    __syncthreads();
  }

  // ---- epilogue: 2 passes over N-halves; stage in LDS, write coalesced ----
  // C frag layout (m89): col=lane&15, row=(lane>>4)*4+j. LDS col swizzle:
  // c2 = col ^ ((lane>>4)<<4) -> 2 lane-groups per bank-half = 2-way (free).
  for (int p = 0; p < 2; ++p) {
    if (p) __syncthreads();             // previous pass read-out done
    if (wn == p) {
#pragma unroll
      for (int fm = 0; fm < 4; fm++) {
#pragma unroll
        for (int fn = 0; fn < 4; fn++) {
          const int colL = fn * 16 + (lane & 15);
          const float bv = bias[n0 + p * 64 + colL];
          const int c2 = colL ^ ((lane >> 4) << 4);
#pragma unroll
          for (int j = 0; j < 4; j++) {
            const int row = wm * 64 + fm * 16 + (lane >> 4) * 4 + j;
            Cs[row * 64 + c2] = acc[fm][fn][j] + bv;
          }
        }
      }
    }
    __syncthreads();
    // read-out: 128 rows x 16 float4; 8 float4 per thread; rows contiguous in global
#pragma unroll
    for (int k = 0; k < 8; k++) {
      const int f   = k * 256 + tid;
      const int row = f >> 4;
      const int c0  = (f & 15) * 4;
      const int c2  = c0 ^ (((row >> 2) & 3) << 4);
      const f32x4 v = *(const f32x4*)&Cs[row * 64 + c2];
      const size_t gbase = (m0 + row) * (size_t)NOUT + n0 + p * 64 + c0;
      if (MODE == 0) {
        f16x4 hv;
        hv[0] = (_Float16)fmaxf(v[0], 0.f);
        hv[1] = (_Float16)fmaxf(v[1], 0.f);
        hv[2] = (_Float16)fmaxf(v[2], 0.f);
        hv[3] = (_Float16)fmaxf(v[3], 0.f);
        *(f16x4*)&((_Float16*)outp)[gbase] = hv;
      } else {
        const f32x4 cv4 = *(const f32x4*)&cvin[gbase];   // same addr this lane rewrites
        f32x4 o;
        o[0] = softplus_f(v[0]) * cv4[0];
        o[1] = softplus_f(v[1]) * cv4[1];
        o[2] = softplus_f(v[2]) * cv4[2];
        o[3] = softplus_f(v[3]) * cv4[3];
        *(f32x4*)&((float*)outp)[gbase] = o;
      }
    }
  }
}

extern "C" void kernel_launch(void* const* d_in, const int* in_sizes, int n_in,
                              void* d_out, int out_size, void* d_ws, size_t ws_size,
                              hipStream_t stream) {
  const float* x     = (const float*)d_in[0];
  const float* rets  = (const float*)d_in[1];
  const float* alpha = (const float*)d_in[2];
  const float* beta  = (const float*)d_in[3];
  const float* omega = (const float*)d_in[4];
  const float* W1    = (const float*)d_in[5];
  const float* b1    = (const float*)d_in[6];
  const float* W2    = (const float*)d_in[7];
  const float* b2    = (const float*)d_in[8];
  float* out = (float*)d_out;

  // workspace layout (~36.5 MB total)
  char* ws = (char*)d_ws;
  _Float16* W1T = (_Float16*)ws;                               // [256][512] f16, 256 KB
  _Float16* W2T = (_Float16*)(ws + (256 << 10));               // [512][256] f16, 256 KB
  float*    Cws = (float*)(ws + (512 << 10));                  // [B][NCH][D] f32, 2 MB
  float*    Vws = (float*)(ws + (512 << 10) + (2 << 20));      // [B][NCH][D] f32, 2 MB
  _Float16* h   = (_Float16*)(ws + (512 << 10) + (4 << 20));   // [M][DH] f16, 32 MB

  // weight prep (tiny)
  transpose_to_f16<<<512, 256, 0, stream>>>(W1, W1T, 512, 256);  // W1T[f][d]=W1[d][f]
  transpose_to_f16<<<512, 256, 0, stream>>>(W2, W2T, 256, 512);  // W2T[d][f]=W2[f][d]

  // GARCH blocked affine scan; cond_var lands in d_out
  garch_chunk <<<B_ * NCH, 512, 0, stream>>>(rets, alpha, beta, omega, Cws);
  garch_scan  <<<B_,       512, 0, stream>>>(beta, Cws, Vws);
  garch_replay<<<B_ * NCH, 512, 0, stream>>>(rets, alpha, beta, omega, Vws, out);

  // h = relu(x @ W1 + b1)  [f16 out]
  gemm_f16<512, 256, 0><<<dim3(M_ / 128, 2), 256, 0, stream>>>(x, W1T, b1, nullptr, h);
  // out = softplus(h @ W2 + b2) * cond_var   (reads cv from d_out, writes d_out)
  gemm_f16<256, 512, 1><<<dim3(M_ / 128, 4), 256, 0, stream>>>(h, W2T, b2, out, out);
}

// Round 10
// 421.726 us; speedup vs baseline: 1.2702x; 1.1068x over previous
//
#include <hip/hip_runtime.h>
#include <hip/hip_bf16.h>
#include <hip/hip_fp16.h>

#define B_   16
#define S_   4096
#define D_   512
#define DH_  256
#define M_   (B_ * S_)      // 65536 rows
#define LC   64             // GARCH chunk length
#define NCH  (S_ / LC)      // 64 chunks

typedef _Float16 f16x8 __attribute__((ext_vector_type(8)));
typedef _Float16 f16x4 __attribute__((ext_vector_type(4)));
typedef float    f32x4 __attribute__((ext_vector_type(4)));

// -------- async global->LDS, 16B per lane (linear LDS dest, per-lane global src) -----
__device__ __forceinline__ void async_copy16(void* lds, const void* g) {
  __builtin_amdgcn_global_load_lds(
      (const __attribute__((address_space(1))) void*)g,
      (__attribute__((address_space(3))) void*)lds, 16, 0, 0);
}

// cheap softplus: max(x,0) + ln2*log2(1+2^(-|x|*log2e));
// exp2f/__log2f lower to near-bare v_exp_f32/v_log_f32 (validated in R9 bench)
__device__ __forceinline__ float softplus_f(float x) {
  const float t = exp2f(-fabsf(x) * 1.44269504f);
  return fmaxf(x, 0.f) + 0.69314718f * __log2f(1.f + t);
}

// ---------------- weight transpose + f16 convert: dst[c][r] = src[r][c] -------------
__global__ void transpose_to_f16(const float* __restrict__ src, _Float16* __restrict__ dst,
                                 int Rr, int Cc) {
  const int idx = blockIdx.x * 256 + threadIdx.x;   // over Rr*Cc
  const int c = idx / Rr;
  const int r = idx - c * Rr;
  dst[idx] = (_Float16)src[(size_t)r * Cc + c];     // coalesced writes
}

// ---------------- GARCH phase 1: per-chunk affine coefficient C ---------------------
// Over chunk c: V_{c+1} = beta^LC * V_c + C_c,  C_c = recurrence started from 0.
__global__ void garch_chunk(const float* __restrict__ ret,
                            const float* __restrict__ pal, const float* __restrict__ pbe,
                            const float* __restrict__ pom, float* __restrict__ Cws) {
  const int d  = threadIdx.x;          // 0..511
  const int bc = blockIdx.x;           // b*NCH + c
  const int b  = bc >> 6;
  const int c  = bc & (NCH - 1);
  const float al = pal[0], be = pbe[0], om = pom[0];
  const float* rp = ret + ((size_t)(b * S_ + c * LC)) * D_ + d;
  float Ca = 0.f;
#pragma unroll 8
  for (int j = 0; j < LC; j++) {
    const float r = rp[(size_t)j * D_];            // coalesced across d
    Ca = fmaf(be, Ca, fmaf(al, r * r, om));
  }
  Cws[(size_t)bc * D_ + d] = Ca;
}

// ---------------- GARCH phase 2: scan over chunks -> chunk-start states Vws ---------
__global__ void garch_scan(const float* __restrict__ pbe, const float* __restrict__ Cws,
                           float* __restrict__ Vws) {
  const int d = threadIdx.x;
  const int b = blockIdx.x;
  float A = pbe[0];
  A = A * A; A = A * A; A = A * A; A = A * A; A = A * A; A = A * A;   // beta^64
  float V = 0.01f;                                                     // INIT_VAR
  for (int c = 0; c < NCH; c++) {
    const size_t idx = ((size_t)(b * NCH + c)) * D_ + d;
    Vws[idx] = V;
    V = fmaf(A, V, Cws[idx]);
  }
}

// ---------------- f16 MFMA GEMM: 128x128 tile, BK=64, XOR-swizzled LDS --------------
// MODE 0: A = fp32 (convert in staging), out = relu(acc+bias) f16; 32KB LDS, 3 blk/CU
// MODE 1: A = f16 (global_load_lds); FUSED epilogue: stage acc+bias in 64KB LDS,
//         then per-column GARCH replay (V from Vws, ret reload) * softplus -> d_out.
//         gemm2 block = 128 aligned rows (2 chunks of one batch) x 128 d-cols.
template<int KDIM, int NOUT, int MODE>
__launch_bounds__(256, MODE ? 2 : 3)
__global__ void gemm_f16(const void* __restrict__ Ap, const _Float16* __restrict__ Bt,
                         const float* __restrict__ bias,
                         const float* __restrict__ retp,   // MODE1: ret base (else null)
                         const float* __restrict__ Vws_g,  // MODE1: chunk-start states
                         const float* __restrict__ gal, const float* __restrict__ gbe,
                         const float* __restrict__ gom,
                         void* outp) {
  __shared__ __align__(16) char smem[MODE ? 65536 : 32768];
  _Float16* As = (_Float16*)smem;            // [128][64] f16, chunk ^= (row&7) swizzle
  _Float16* Bs = (_Float16*)(smem + 16384);  // B^T tile [n][k]

  const int tid  = threadIdx.x;
  const int lane = tid & 63;
  const int w    = tid >> 6;
  const int wm   = w >> 1, wn = w & 1;          // 2x2 wave grid, 64x64 per wave
  const size_t m0 = (size_t)blockIdx.x * 128;
  const int    n0 = blockIdx.y * 128;

  f32x4 acc[4][4];
#pragma unroll
  for (int i = 0; i < 4; i++)
#pragma unroll
    for (int j = 0; j < 4; j++)
      acc[i][j] = (f32x4){0.f, 0.f, 0.f, 0.f};

  const _Float16* hA = (const _Float16*)Ap;
  const float*    fA = (const float*)Ap;

  for (int kt = 0; kt < KDIM; kt += 64) {
    // ---- stage B (f16, pre-transposed): linear LDS dest + inverse-swizzled source ----
#pragma unroll
    for (int rr = 0; rr < 4; rr++) {
      const int task = rr * 256 + tid;
      const int row = task >> 3, pos = task & 7;
      const int dc = pos ^ (row & 7);
      async_copy16(&Bs[task * 8], &Bt[(size_t)(n0 + row) * KDIM + kt + dc * 8]);
    }
    if (MODE == 1) {
#pragma unroll
      for (int rr = 0; rr < 4; rr++) {
        const int task = rr * 256 + tid;
        const int row = task >> 3, pos = task & 7;
        const int dc = pos ^ (row & 7);
        async_copy16(&As[task * 8], &hA[(m0 + row) * (size_t)KDIM + kt + dc * 8]);
      }
    } else {
      // fp32 -> f16 reg-staged convert, swizzled ds_write_b128
#pragma unroll
      for (int rr = 0; rr < 4; rr++) {
        const int task = rr * 256 + tid;
        const int row = task >> 3, dc = task & 7;
        const float* sp = &fA[(m0 + row) * (size_t)KDIM + kt + dc * 8];
        const float4 v0 = *(const float4*)(sp);
        const float4 v1 = *(const float4*)(sp + 4);
        f16x8 hv;
        hv[0] = (_Float16)v0.x; hv[1] = (_Float16)v0.y;
        hv[2] = (_Float16)v0.z; hv[3] = (_Float16)v0.w;
        hv[4] = (_Float16)v1.x; hv[5] = (_Float16)v1.y;
        hv[6] = (_Float16)v1.z; hv[7] = (_Float16)v1.w;
        const int pos = dc ^ (row & 7);
        *(f16x8*)&As[row * 64 + pos * 8] = hv;
      }
    }
    __syncthreads();   // compiler drains vmcnt+lgkmcnt before s_barrier

    // ---- fragments (swizzled ds_read_b128, conflict-free) + MFMA ----
    f16x8 af[4][2], bf[4][2];
#pragma unroll
    for (int f = 0; f < 4; f++) {
#pragma unroll
      for (int kk = 0; kk < 2; kk++) {
        const int k8 = kk * 4 + (lane >> 4);
        const int ar = wm * 64 + f * 16 + (lane & 15);
        af[f][kk] = *(const f16x8*)&As[ar * 64 + ((k8 ^ (ar & 7)) * 8)];
        const int br = wn * 64 + f * 16 + (lane & 15);
        bf[f][kk] = *(const f16x8*)&Bs[br * 64 + ((k8 ^ (br & 7)) * 8)];
      }
    }
#pragma unroll
    for (int kk = 0; kk < 2; kk++)
#pragma unroll
      for (int fm = 0; fm < 4; fm++)
#pragma unroll
        for (int fn = 0; fn < 4; fn++)
          acc[fm][fn] = __builtin_amdgcn_mfma_f32_16x16x32_f16(af[fm][kk], bf[fn][kk],
                                                               acc[fm][fn], 0, 0, 0);
    __syncthreads();
  }

  if (MODE == 1) {
    // ---- fused epilogue: stage [2][64][128] f32 (acc+bias), then GARCH scan ----
    // C frag (m89): col=lane&15, row=(lane>>4)*4+j; wave wm owns chunk-half wm.
    // Swizzle colS = colG ^ ((rloc>>2)&3)<<4: write 2-way (free), read 2-way (free).
    float* Cs = (float*)smem;
#pragma unroll
    for (int fm = 0; fm < 4; fm++)
#pragma unroll
      for (int fn = 0; fn < 4; fn++) {
        const int colG = wn * 64 + fn * 16 + (lane & 15);
        const float bv = bias[n0 + colG];
#pragma unroll
        for (int j = 0; j < 4; j++) {
          const int rloc = fm * 16 + (lane >> 4) * 4 + j;
          const int colS = colG ^ (((rloc >> 2) & 3) << 4);
          Cs[wm * 8192 + rloc * 128 + colS] = acc[fm][fn][j] + bv;
        }
      }
    __syncthreads();
    // scan: thread -> (half = tid>>7, col = tid&127); rows m0..m0+127 = 2 chunks of
    // batch b (m0 is 128-aligned, S=4096 -> chunk boundaries align).
    const int half = tid >> 7;
    const int col  = tid & 127;
    const int d    = n0 + col;
    const size_t mrow0 = m0 + half * 64;
    const int b  = (int)(m0 >> 12);                 // m0 / S_
    const int ch = (int)((m0 & 4095) >> 6) + half;  // chunk index within batch
    float V = Vws_g[((size_t)(b * NCH + ch)) * D_ + d];
    const float al = gal[0], be = gbe[0], om = gom[0];
    float* oo = (float*)outp;
#pragma unroll 8
    for (int j = 0; j < LC; j++) {
      const size_t gidx = (mrow0 + j) * (size_t)D_ + d;   // 512B-coalesced across col
      const int colS = col ^ (((j >> 2) & 3) << 4);
      const float a = Cs[half * 8192 + j * 128 + colS];
      oo[gidx] = softplus_f(a) * V;                        // out = softplus * cv[j]
      const float r = retp[gidx];                          // ret[row j] -> cv[j+1]
      V = fmaf(be, V, fmaf(al * r, r, om));
    }
  } else {
    // ---- MODE 0 epilogue: 2 passes over N-halves; stage in LDS, write coalesced ----
    float* Cs = (float*)smem;
    for (int p = 0; p < 2; ++p) {
      if (p) __syncthreads();             // previous pass read-out done
      if (wn == p) {
#pragma unroll
        for (int fm = 0; fm < 4; fm++) {
#pragma unroll
          for (int fn = 0; fn < 4; fn++) {
            const int colL = fn * 16 + (lane & 15);
            const float bv = bias[n0 + p * 64 + colL];
            const int c2 = colL ^ ((lane >> 4) << 4);
#pragma unroll
            for (int j = 0; j < 4; j++) {
              const int row = wm * 64 + fm * 16 + (lane >> 4) * 4 + j;
              Cs[row * 64 + c2] = acc[fm][fn][j] + bv;
            }
          }
        }
      }
      __syncthreads();
      // read-out: 128 rows x 16 float4; 8 float4 per thread
#pragma unroll
      for (int k = 0; k < 8; k++) {
        const int f   = k * 256 + tid;
        const int row = f >> 4;
        const int c0  = (f & 15) * 4;
        const int c2  = c0 ^ (((row >> 2) & 3) << 4);
        const f32x4 v = *(const f32x4*)&Cs[row * 64 + c2];
        const size_t gbase = (m0 + row) * (size_t)NOUT + n0 + p * 64 + c0;
        f16x4 hv;
        hv[0] = (_Float16)fmaxf(v[0], 0.f);
        hv[1] = (_Float16)fmaxf(v[1], 0.f);
        hv[2] = (_Float16)fmaxf(v[2], 0.f);
        hv[3] = (_Float16)fmaxf(v[3], 0.f);
        *(f16x4*)&((_Float16*)outp)[gbase] = hv;
      }
    }
  }
}

extern "C" void kernel_launch(void* const* d_in, const int* in_sizes, int n_in,
                              void* d_out, int out_size, void* d_ws, size_t ws_size,
                              hipStream_t stream) {
  const float* x     = (const float*)d_in[0];
  const float* rets  = (const float*)d_in[1];
  const float* alpha = (const float*)d_in[2];
  const float* beta  = (const float*)d_in[3];
  const float* omega = (const float*)d_in[4];
  const float* W1    = (const float*)d_in[5];
  const float* b1    = (const float*)d_in[6];
  const float* W2    = (const float*)d_in[7];
  const float* b2    = (const float*)d_in[8];
  float* out = (float*)d_out;

  // workspace layout (~36.5 MB total)
  char* ws = (char*)d_ws;
  _Float16* W1T = (_Float16*)ws;                               // [256][512] f16, 256 KB
  _Float16* W2T = (_Float16*)(ws + (256 << 10));               // [512][256] f16, 256 KB
  float*    Cws = (float*)(ws + (512 << 10));                  // [B][NCH][D] f32, 2 MB
  float*    Vws = (float*)(ws + (512 << 10) + (2 << 20));      // [B][NCH][D] f32, 2 MB
  _Float16* h   = (_Float16*)(ws + (512 << 10) + (4 << 20));   // [M][DH] f16, 32 MB

  // weight prep (tiny)
  transpose_to_f16<<<512, 256, 0, stream>>>(W1, W1T, 512, 256);  // W1T[f][d]=W1[d][f]
  transpose_to_f16<<<512, 256, 0, stream>>>(W2, W2T, 256, 512);  // W2T[d][f]=W2[f][d]

  // GARCH blocked affine scan: chunk coefficients + chunk-start states (replay fused
  // into gemm2's epilogue)
  garch_chunk <<<B_ * NCH, 512, 0, stream>>>(rets, alpha, beta, omega, Cws);
  garch_scan  <<<B_,       512, 0, stream>>>(beta, Cws, Vws);

  // h = relu(x @ W1 + b1)  [f16 out]
  gemm_f16<512, 256, 0><<<dim3(M_ / 128, 2), 256, 0, stream>>>(
      x, W1T, b1, nullptr, nullptr, nullptr, nullptr, nullptr, h);
  // out = softplus(h @ W2 + b2) * cond_var  (cv recomputed in-register from Vws+ret)
  gemm_f16<256, 512, 1><<<dim3(M_ / 128, 4), 256, 0, stream>>>(
      h, W2T, b2, rets, Vws, alpha, beta, omega, out);
}

// Round 11
// 405.681 us; speedup vs baseline: 1.3204x; 1.0395x over previous
//
#include <hip/hip_runtime.h>
#include <hip/hip_bf16.h>
#include <hip/hip_fp16.h>

#define B_   16
#define S_   4096
#define D_   512
#define DH_  256
#define M_   (B_ * S_)      // 65536 rows
#define LC   64             // GARCH chunk length
#define NCH  (S_ / LC)      // 64 chunks

typedef _Float16 f16x8 __attribute__((ext_vector_type(8)));
typedef _Float16 f16x4 __attribute__((ext_vector_type(4)));
typedef float    f32x4 __attribute__((ext_vector_type(4)));

// -------- async global->LDS, 16B per lane (linear LDS dest, per-lane global src) -----
__device__ __forceinline__ void async_copy16(void* lds, const void* g) {
  __builtin_amdgcn_global_load_lds(
      (const __attribute__((address_space(1))) void*)g,
      (__attribute__((address_space(3))) void*)lds, 16, 0, 0);
}

// cheap softplus: max(x,0) + ln2*log2(1+2^(-|x|*log2e));
// exp2f/__log2f lower to near-bare v_exp_f32/v_log_f32 (validated R9/R10)
__device__ __forceinline__ float softplus_f(float x) {
  const float t = exp2f(-fabsf(x) * 1.44269504f);
  return fmaxf(x, 0.f) + 0.69314718f * __log2f(1.f + t);
}

// ---------------- weight transpose + f16 convert: dst[c][r] = src[r][c] -------------
__global__ void transpose_to_f16(const float* __restrict__ src, _Float16* __restrict__ dst,
                                 int Rr, int Cc) {
  const int idx = blockIdx.x * 256 + threadIdx.x;   // over Rr*Cc
  const int c = idx / Rr;
  const int r = idx - c * Rr;
  dst[idx] = (_Float16)src[(size_t)r * Cc + c];     // coalesced writes
}

// ---------------- GARCH phase 1: per-chunk affine coefficient C ---------------------
// Over chunk c: V_{c+1} = beta^LC * V_c + C_c,  C_c = recurrence started from 0.
__global__ void garch_chunk(const float* __restrict__ ret,
                            const float* __restrict__ pal, const float* __restrict__ pbe,
                            const float* __restrict__ pom, float* __restrict__ Cws) {
  const int d  = threadIdx.x;          // 0..511
  const int bc = blockIdx.x;           // b*NCH + c
  const int b  = bc >> 6;
  const int c  = bc & (NCH - 1);
  const float al = pal[0], be = pbe[0], om = pom[0];
  const float* rp = ret + ((size_t)(b * S_ + c * LC)) * D_ + d;
  float Ca = 0.f;
#pragma unroll 8
  for (int j = 0; j < LC; j++) {
    const float r = rp[(size_t)j * D_];            // coalesced across d
    Ca = fmaf(be, Ca, fmaf(al, r * r, om));
  }
  Cws[(size_t)bc * D_ + d] = Ca;
}

// ---------------- GARCH phase 2: scan over chunks -> chunk-start states Vws ---------
__global__ void garch_scan(const float* __restrict__ pbe, const float* __restrict__ Cws,
                           float* __restrict__ Vws) {
  const int d = threadIdx.x;
  const int b = blockIdx.x;
  float A = pbe[0];
  A = A * A; A = A * A; A = A * A; A = A * A; A = A * A; A = A * A;   // beta^64
  float V = 0.01f;                                                     // INIT_VAR
  for (int c = 0; c < NCH; c++) {
    const size_t idx = ((size_t)(b * NCH + c)) * D_ + d;
    Vws[idx] = V;
    V = fmaf(A, V, Cws[idx]);
  }
}

// ---------------- f16 MFMA GEMM: 128x128 tile, BK=64, XOR-swizzled LDS --------------
// MODE 0: A = fp32 (convert in staging), out = relu(acc+bias) f16.
// MODE 1: A = f16 (global_load_lds); FUSED epilogue: stage f16(softplus(acc+bias)) in
//         32KB LDS, then per-column GARCH replay (V from Vws, ret reload) -> d_out.
//         gemm2 block = 128 aligned rows (2 chunks of one batch) x 128 d-cols.
// 32KB LDS + lb(256,4): 4 blocks/CU (128KB LDS, VGPR cap 128 >= measured 68/88).
template<int KDIM, int NOUT, int MODE>
__launch_bounds__(256, 4)
__global__ void gemm_f16(const void* __restrict__ Ap, const _Float16* __restrict__ Bt,
                         const float* __restrict__ bias,
                         const float* __restrict__ retp,   // MODE1: ret base (else null)
                         const float* __restrict__ Vws_g,  // MODE1: chunk-start states
                         const float* __restrict__ gal, const float* __restrict__ gbe,
                         const float* __restrict__ gom,
                         void* outp) {
  __shared__ __align__(16) char smem[32768];
  _Float16* As = (_Float16*)smem;            // [128][64] f16, chunk ^= (row&7) swizzle
  _Float16* Bs = (_Float16*)(smem + 16384);  // B^T tile [n][k]

  const int tid  = threadIdx.x;
  const int lane = tid & 63;
  const int w    = tid >> 6;
  const int wm   = w >> 1, wn = w & 1;          // 2x2 wave grid, 64x64 per wave
  const size_t m0 = (size_t)blockIdx.x * 128;
  const int    n0 = blockIdx.y * 128;

  f32x4 acc[4][4];
#pragma unroll
  for (int i = 0; i < 4; i++)
#pragma unroll
    for (int j = 0; j < 4; j++)
      acc[i][j] = (f32x4){0.f, 0.f, 0.f, 0.f};

  const _Float16* hA = (const _Float16*)Ap;
  const float*    fA = (const float*)Ap;

  for (int kt = 0; kt < KDIM; kt += 64) {
    // ---- stage B (f16, pre-transposed): linear LDS dest + inverse-swizzled source ----
#pragma unroll
    for (int rr = 0; rr < 4; rr++) {
      const int task = rr * 256 + tid;
      const int row = task >> 3, pos = task & 7;
      const int dc = pos ^ (row & 7);
      async_copy16(&Bs[task * 8], &Bt[(size_t)(n0 + row) * KDIM + kt + dc * 8]);
    }
    if (MODE == 1) {
#pragma unroll
      for (int rr = 0; rr < 4; rr++) {
        const int task = rr * 256 + tid;
        const int row = task >> 3, pos = task & 7;
        const int dc = pos ^ (row & 7);
        async_copy16(&As[task * 8], &hA[(m0 + row) * (size_t)KDIM + kt + dc * 8]);
      }
    } else {
      // fp32 -> f16 reg-staged convert, swizzled ds_write_b128
#pragma unroll
      for (int rr = 0; rr < 4; rr++) {
        const int task = rr * 256 + tid;
        const int row = task >> 3, dc = task & 7;
        const float* sp = &fA[(m0 + row) * (size_t)KDIM + kt + dc * 8];
        const float4 v0 = *(const float4*)(sp);
        const float4 v1 = *(const float4*)(sp + 4);
        f16x8 hv;
        hv[0] = (_Float16)v0.x; hv[1] = (_Float16)v0.y;
        hv[2] = (_Float16)v0.z; hv[3] = (_Float16)v0.w;
        hv[4] = (_Float16)v1.x; hv[5] = (_Float16)v1.y;
        hv[6] = (_Float16)v1.z; hv[7] = (_Float16)v1.w;
        const int pos = dc ^ (row & 7);
        *(f16x8*)&As[row * 64 + pos * 8] = hv;
      }
    }
    __syncthreads();   // compiler drains vmcnt+lgkmcnt before s_barrier

    // ---- fragments (swizzled ds_read_b128, conflict-free) + MFMA ----
    f16x8 af[4][2], bf[4][2];
#pragma unroll
    for (int f = 0; f < 4; f++) {
#pragma unroll
      for (int kk = 0; kk < 2; kk++) {
        const int k8 = kk * 4 + (lane >> 4);
        const int ar = wm * 64 + f * 16 + (lane & 15);
        af[f][kk] = *(const f16x8*)&As[ar * 64 + ((k8 ^ (ar & 7)) * 8)];
        const int br = wn * 64 + f * 16 + (lane & 15);
        bf[f][kk] = *(const f16x8*)&Bs[br * 64 + ((k8 ^ (br & 7)) * 8)];
      }
    }
#pragma unroll
    for (int kk = 0; kk < 2; kk++)
#pragma unroll
      for (int fm = 0; fm < 4; fm++)
#pragma unroll
        for (int fn = 0; fn < 4; fn++)
          acc[fm][fn] = __builtin_amdgcn_mfma_f32_16x16x32_f16(af[fm][kk], bf[fn][kk],
                                                               acc[fm][fn], 0, 0, 0);
    __syncthreads();
  }

  if (MODE == 1) {
    // ---- fused epilogue: stage f16(softplus(acc+bias)) [2][64][128], then scan ----
    // C frag (m89): col=lane&15, row=(lane>>4)*4+j; wave wm owns chunk-half wm.
    // Swizzle colS = colG ^ ((rloc>>2)&3)<<4 (f16): write-side 4 lane-groups map to
    // disjoint 8-bank sets (2-way, free); read-side 128B contiguous (2-way, free).
    _Float16* Ch = (_Float16*)smem;
#pragma unroll
    for (int fm = 0; fm < 4; fm++)
#pragma unroll
      for (int fn = 0; fn < 4; fn++) {
        const int colG = wn * 64 + fn * 16 + (lane & 15);
        const float bv = bias[n0 + colG];
#pragma unroll
        for (int j = 0; j < 4; j++) {
          const int rloc = fm * 16 + (lane >> 4) * 4 + j;
          const int colS = colG ^ (((rloc >> 2) & 3) << 4);
          Ch[wm * 8192 + rloc * 128 + colS] = (_Float16)softplus_f(acc[fm][fn][j] + bv);
        }
      }
    __syncthreads();
    // scan: thread -> (half = tid>>7, col = tid&127); rows m0..m0+127 = 2 chunks of
    // batch b (m0 is 128-aligned, S=4096 -> chunk boundaries align).
    const int half = tid >> 7;
    const int col  = tid & 127;
    const int d    = n0 + col;
    const size_t mrow0 = m0 + half * 64;
    const int b  = (int)(m0 >> 12);                 // m0 / S_
    const int ch = (int)((m0 & 4095) >> 6) + half;  // chunk index within batch
    float V = Vws_g[((size_t)(b * NCH + ch)) * D_ + d];
    const float al = gal[0], be = gbe[0], om = gom[0];
    float* oo = (float*)outp;
#pragma unroll 8
    for (int j = 0; j < LC; j++) {
      const size_t gidx = (mrow0 + j) * (size_t)D_ + d;   // 512B-coalesced across col
      const int colS = col ^ (((j >> 2) & 3) << 4);
      const float sp = (float)Ch[half * 8192 + j * 128 + colS];
      oo[gidx] = sp * V;                                   // out = softplus * cv[j]
      const float r = retp[gidx];                          // ret[row j] -> cv[j+1]
      V = fmaf(be, V, fmaf(al * r, r, om));
    }
  } else {
    // ---- MODE 0 epilogue: 2 passes over N-halves; stage in LDS, write coalesced ----
    float* Cs = (float*)smem;
    for (int p = 0; p < 2; ++p) {
      if (p) __syncthreads();             // previous pass read-out done
      if (wn == p) {
#pragma unroll
        for (int fm = 0; fm < 4; fm++) {
#pragma unroll
          for (int fn = 0; fn < 4; fn++) {
            const int colL = fn * 16 + (lane & 15);
            const float bv = bias[n0 + p * 64 + colL];
            const int c2 = colL ^ ((lane >> 4) << 4);
#pragma unroll
            for (int j = 0; j < 4; j++) {
              const int row = wm * 64 + fm * 16 + (lane >> 4) * 4 + j;
              Cs[row * 64 + c2] = acc[fm][fn][j] + bv;
            }
          }
        }
      }
      __syncthreads();
      // read-out: 128 rows x 16 float4; 8 float4 per thread
#pragma unroll
      for (int k = 0; k < 8; k++) {
        const int f   = k * 256 + tid;
        const int row = f >> 4;
        const int c0  = (f & 15) * 4;
        const int c2  = c0 ^ (((row >> 2) & 3) << 4);
        const f32x4 v = *(const f32x4*)&Cs[row * 64 + c2];
        const size_t gbase = (m0 + row) * (size_t)NOUT + n0 + p * 64 + c0;
        f16x4 hv;
        hv[0] = (_Float16)fmaxf(v[0], 0.f);
        hv[1] = (_Float16)fmaxf(v[1], 0.f);
        hv[2] = (_Float16)fmaxf(v[2], 0.f);
        hv[3] = (_Float16)fmaxf(v[3], 0.f);
        *(f16x4*)&((_Float16*)outp)[gbase] = hv;
      }
    }
  }
}

extern "C" void kernel_launch(void* const* d_in, const int* in_sizes, int n_in,
                              void* d_out, int out_size, void* d_ws, size_t ws_size,
                              hipStream_t stream) {
  const float* x     = (const float*)d_in[0];
  const float* rets  = (const float*)d_in[1];
  const float* alpha = (const float*)d_in[2];
  const float* beta  = (const float*)d_in[3];
  const float* omega = (const float*)d_in[4];
  const float* W1    = (const float*)d_in[5];
  const float* b1    = (const float*)d_in[6];
  const float* W2    = (const float*)d_in[7];
  const float* b2    = (const float*)d_in[8];
  float* out = (float*)d_out;

  // workspace layout (~36.5 MB total)
  char* ws = (char*)d_ws;
  _Float16* W1T = (_Float16*)ws;                               // [256][512] f16, 256 KB
  _Float16* W2T = (_Float16*)(ws + (256 << 10));               // [512][256] f16, 256 KB
  float*    Cws = (float*)(ws + (512 << 10));                  // [B][NCH][D] f32, 2 MB
  float*    Vws = (float*)(ws + (512 << 10) + (2 << 20));      // [B][NCH][D] f32, 2 MB
  _Float16* h   = (_Float16*)(ws + (512 << 10) + (4 << 20));   // [M][DH] f16, 32 MB

  // weight prep (tiny)
  transpose_to_f16<<<512, 256, 0, stream>>>(W1, W1T, 512, 256);  // W1T[f][d]=W1[d][f]
  transpose_to_f16<<<512, 256, 0, stream>>>(W2, W2T, 256, 512);  // W2T[d][f]=W2[f][d]

  // h = relu(x @ W1 + b1)  [f16 out]  — runs FIRST so its x-stream doesn't evict
  // ret from L3 between garch_chunk's read and gemm2's re-read.
  gemm_f16<512, 256, 0><<<dim3(M_ / 128, 2), 256, 0, stream>>>(
      x, W1T, b1, nullptr, nullptr, nullptr, nullptr, nullptr, h);

  // GARCH blocked affine scan: chunk coefficients + chunk-start states (replay fused
  // into gemm2's epilogue). ret (134 MB) stays L3-hot for gemm2.
  garch_chunk <<<B_ * NCH, 512, 0, stream>>>(rets, alpha, beta, omega, Cws);
  garch_scan  <<<B_,       512, 0, stream>>>(beta, Cws, Vws);

  // out = softplus(h @ W2 + b2) * cond_var  (cv recomputed in-register from Vws+ret)
  gemm_f16<256, 512, 1><<<dim3(M_ / 128, 4), 256, 0, stream>>>(
      h, W2T, b2, rets, Vws, alpha, beta, omega, out);
}